// Round 7
// baseline (110.580 us; speedup 1.0000x reference)
//
#include <hip/hip_runtime.h>

typedef unsigned short u16;
typedef unsigned int u32;
typedef float f32x4 __attribute__((ext_vector_type(4)));
typedef float f32x16 __attribute__((ext_vector_type(16)));
typedef _Float16 h16x8 __attribute__((ext_vector_type(8)));
typedef u32 u32x4 __attribute__((ext_vector_type(4)));
typedef u32 u32x2 __attribute__((ext_vector_type(2)));
typedef u16 u16x4 __attribute__((ext_vector_type(4)));

#define NB 8
#define CC 192
#define OO 96
#define NN 4096
#define NSPLIT 3
#define XPAD 200   // proj LDS row pad
#define LOG2E 1.4426950408889634f

static __device__ __forceinline__ u16 f2h(float f) {
  _Float16 h = (_Float16)f;
  return __builtin_bit_cast(u16, h);
}
static __device__ __forceinline__ void gl_lds16(const u16* g, u16* l) {
  __builtin_amdgcn_global_load_lds(
      (const __attribute__((address_space(1))) void*)g,
      (__attribute__((address_space(3))) void*)l, 16, 0, 0);
}
// ret0 = [a.lanes0-31 | b.lanes0-31], ret1 = [a.lanes32-63 | b.lanes32-63]
static __device__ __forceinline__ void plane_swap(u32& a, u32& b) {
  u32x2 r = __builtin_amdgcn_permlane32_swap(a, b, false, false);
  a = r[0]; b = r[1];
}
static __device__ __forceinline__ float half_combine_max(float x) {
  u32 a = __builtin_bit_cast(u32, x), b = a;
  plane_swap(a, b);
  return fmaxf(__builtin_bit_cast(float, a), __builtin_bit_cast(float, b));
}
static __device__ __forceinline__ float half_combine_sum(float x) {
  u32 a = __builtin_bit_cast(u32, x), b = a;
  plane_swap(a, b);
  return __builtin_bit_cast(float, a) + __builtin_bit_cast(float, b);
}
static __device__ __forceinline__ float max3f(float a, float b, float c) {
  return fmaxf(fmaxf(a, b), c);   // clang fuses to v_max3_f32
}

// ---------------- Kernel 1: theta/phi/g projections as fp16 MFMA GEMMs ----------------
// Outputs in MFMA-fragment-preswizzled layouts (32x32x16 frags). Theta side is
// pre-scaled by log2(e) so attention can use native exp2.
__global__ __launch_bounds__(256) void proj_kernel(
    const float* __restrict__ x,
    const float* __restrict__ g_w, const float* __restrict__ g_b,
    const float* __restrict__ th_w, const float* __restrict__ th_b,
    const float* __restrict__ ph_w, const float* __restrict__ ph_b,
    u16* __restrict__ QB, u16* __restrict__ KA, u16* __restrict__ VA)
{
  __shared__ __align__(16) u16 Xs[64][XPAD];
  __shared__ __align__(16) u16 Ws[96][XPAD];
  const int b = blockIdx.y, n0 = blockIdx.x * 64, tid = threadIdx.x;
  const int lane = tid & 63, wv = tid >> 6, l15 = lane & 15, lg = lane >> 4;

  #pragma unroll
  for (int it = 0; it < 12; ++it) {
    int idx = tid + it * 256;
    int c = idx >> 4, q = idx & 15;
    float4 v = *(const float4*)(x + ((size_t)(b * CC + c)) * NN + n0 + q * 4);
    Xs[q * 4 + 0][c] = f2h(v.x); Xs[q * 4 + 1][c] = f2h(v.y);
    Xs[q * 4 + 2][c] = f2h(v.z); Xs[q * 4 + 3][c] = f2h(v.w);
  }

  for (int p = 0; p < 3; ++p) {
    const float* w    = (p == 0) ? th_w : (p == 1) ? ph_w : g_w;
    const float* bias = (p == 0) ? th_b : (p == 1) ? ph_b : g_b;
    const float scale = (p == 0) ? LOG2E : 1.0f;
    __syncthreads();
    #pragma unroll
    for (int it = 0; it < 18; ++it) {
      int idx = tid + it * 256;
      int r = idx / 48, q = idx % 48;
      float4 v = *(const float4*)(w + r * CC + q * 4);
      u16x4 hh; hh[0] = f2h(v.x * scale); hh[1] = f2h(v.y * scale);
      hh[2] = f2h(v.z * scale); hh[3] = f2h(v.w * scale);
      *(u16x4*)&Ws[r][q * 4] = hh;
    }
    __syncthreads();

    f32x4 acc[6];
    #pragma unroll
    for (int of = 0; of < 6; ++of) acc[of] = (f32x4){0.f, 0.f, 0.f, 0.f};
    #pragma unroll
    for (int ks = 0; ks < 6; ++ks) {
      h16x8 xa = *(const h16x8*)&Xs[wv * 16 + l15][ks * 32 + lg * 8];
      #pragma unroll
      for (int of = 0; of < 6; ++of) {
        h16x8 wf = *(const h16x8*)&Ws[of * 16 + l15][ks * 32 + lg * 8];
        if (p < 2) acc[of] = __builtin_amdgcn_mfma_f32_16x16x32_f16(xa, wf, acc[of], 0, 0, 0);
        else       acc[of] = __builtin_amdgcn_mfma_f32_16x16x32_f16(wf, xa, acc[of], 0, 0, 0);
      }
    }

    if (p < 2) {   // C[n][o] -> QB / KA (A/B-frag preswizzle)
      u16* dst = (p == 0) ? QB : KA;
      #pragma unroll
      for (int of = 0; of < 6; ++of) {
        int o = of * 16 + l15;
        float bo = bias[o] * scale;
        int kch = of * 2 + (l15 >> 3);
        #pragma unroll
        for (int r = 0; r < 4; ++r) {
          int n = n0 + wv * 16 + lg * 4 + r;
          int idx = (b * 128 + (n >> 5)) * 3072 + (kch * 32 + (n & 31)) * 8 + (o & 7);
          dst[idx] = f2h(acc[of][r] + bo);
        }
      }
    } else {       // C[o][m] -> VA (V^T A-frag preswizzle)
      #pragma unroll
      for (int of = 0; of < 6; ++of) {
        #pragma unroll
        for (int r = 0; r < 4; ++r) {
          int o = of * 16 + lg * 4 + r;
          int m = n0 + wv * 16 + l15;
          int idx = (b * 256 + (m >> 4)) * 1536 +
                    (((o >> 5) * 2 + ((m >> 3) & 1)) * 32 + (o & 31)) * 8 + (m & 7);
          VA[idx] = f2h(acc[of][r] + bias[o]);
        }
      }
    }
  }
}

// ---------------- Kernel 2: flash attention core ----------------
// 4 waves x 32 q-rows. 64-m tiles double-buffered; both 32-m chunks computed with
// interleaved MFMAs + ONE joint softmax (log2 domain, defer-max, in-register P).
__global__ __launch_bounds__(256, 3) void attn_kernel(
    const u16* __restrict__ QB, const u16* __restrict__ KA,
    const u16* __restrict__ VA, u16* __restrict__ yP, float* __restrict__ ml)
{
  __shared__ __align__(16) u16 Ks[2][6144];
  __shared__ __align__(16) u16 Vs[2][6144];
  const int b   = blockIdx.x;           // XCD-swizzle: id%8 == batch
  const int qt  = blockIdx.y;
  const int sp  = blockIdx.z;
  const int tid = threadIdx.x;
  const int lane = tid & 63;
  const int wv  = tid >> 6;
  const int l31 = lane & 31;
  const int h   = lane >> 5;

  const int t_start = (64 * sp) / NSPLIT;
  const int t_end   = (64 * (sp + 1)) / NSPLIT;
  const int nt = t_end - t_start;

  const int nc = qt * 4 + wv;
  const u16* qb = QB + (size_t)(b * 128 + nc) * 3072;
  h16x8 qf[6];
  #pragma unroll
  for (int ks = 0; ks < 6; ++ks)
    qf[ks] = *(const h16x8*)(qb + ((ks * 2 + h) * 32 + l31) * 8);

  const u16* KAb = KA + (size_t)b * (128 * 3072);
  const u16* VAb = VA + (size_t)b * (256 * 1536);

  f32x16 acc[3];
  #pragma unroll
  for (int ob = 0; ob < 3; ++ob)
    #pragma unroll
    for (int i = 0; i < 16; ++i) acc[ob][i] = 0.f;
  float m_run = -3.0e38f, l_run = 0.f;   // log2-domain running max

  // prologue stage: tile = 12288 B; 256 thr x 16 B x 3 iters per operand
  {
    const u16* gk = KAb + (size_t)t_start * 6144;
    const u16* gv = VAb + (size_t)t_start * 6144;
    #pragma unroll
    for (int i = 0; i < 3; ++i) gl_lds16(gk + tid * 8 + i * 2048, &Ks[0][tid * 8 + i * 2048]);
    #pragma unroll
    for (int i = 0; i < 3; ++i) gl_lds16(gv + tid * 8 + i * 2048, &Vs[0][tid * 8 + i * 2048]);
  }

  for (int t = 0; t < nt; ++t) {
    const int bf = t & 1;
    if (t + 1 < nt) {
      const u16* gk = KAb + (size_t)(t_start + t + 1) * 6144;
      const u16* gv = VAb + (size_t)(t_start + t + 1) * 6144;
      #pragma unroll
      for (int i = 0; i < 3; ++i) gl_lds16(gk + tid * 8 + i * 2048, &Ks[bf ^ 1][tid * 8 + i * 2048]);
      #pragma unroll
      for (int i = 0; i < 3; ++i) gl_lds16(gv + tid * 8 + i * 2048, &Vs[bf ^ 1][tid * 8 + i * 2048]);
      asm volatile("s_waitcnt vmcnt(6)" ::: "memory");
    } else {
      asm volatile("s_waitcnt vmcnt(0)" ::: "memory");
    }
    __builtin_amdgcn_s_barrier();
    __builtin_amdgcn_sched_barrier(0);

    // QK^T both chunks, interleaved (independent MFMA chains)
    f32x16 S0, S1;
    #pragma unroll
    for (int i = 0; i < 16; ++i) { S0[i] = 0.f; S1[i] = 0.f; }
    const u16* kb0 = &Ks[bf][0];
    const u16* kb1 = &Ks[bf][3072];
    __builtin_amdgcn_s_setprio(1);
    #pragma unroll
    for (int ks = 0; ks < 6; ++ks) {
      h16x8 kf0 = *(const h16x8*)(kb0 + ((ks * 2 + h) * 32 + l31) * 8);
      S0 = __builtin_amdgcn_mfma_f32_32x32x16_f16(kf0, qf[ks], S0, 0, 0, 0);
      h16x8 kf1 = *(const h16x8*)(kb1 + ((ks * 2 + h) * 32 + l31) * 8);
      S1 = __builtin_amdgcn_mfma_f32_32x32x16_f16(kf1, qf[ks], S1, 0, 0, 0);
    }
    __builtin_amdgcn_s_setprio(0);

    // joint row max over both chunks (v_max3 tree + cross-half swap)
    float v[16];
    #pragma unroll
    for (int i = 0; i < 16; ++i) v[i] = fmaxf(S0[i], S1[i]);
    float t0 = max3f(v[0], v[1], v[2]),  t1 = max3f(v[3], v[4], v[5]);
    float t2 = max3f(v[6], v[7], v[8]),  t3 = max3f(v[9], v[10], v[11]);
    float t4 = max3f(v[12], v[13], v[14]);
    float pmax = half_combine_max(fmaxf(max3f(t0, t1, t2), max3f(t3, t4, v[15])));
    // defer-max rescale (threshold 8 nats = 11.54 bits)
    if (__ballot(pmax > m_run + 11.5416f)) {
      float mn = fmaxf(m_run, pmax);
      float sc = exp2f(m_run - mn);
      m_run = mn; l_run *= sc;
      #pragma unroll
      for (int ob = 0; ob < 3; ++ob)
        #pragma unroll
        for (int i = 0; i < 16; ++i) acc[ob][i] *= sc;
    }
    // P = exp2(S - m), joint sum
    float p0[16], p1[16];
    #pragma unroll
    for (int i = 0; i < 16; ++i) { p0[i] = exp2f(S0[i] - m_run); p1[i] = exp2f(S1[i] - m_run); }
    #pragma unroll
    for (int i = 0; i < 16; ++i) v[i] = p0[i] + p1[i];
    #pragma unroll
    for (int st = 8; st >= 1; st >>= 1)
      #pragma unroll
      for (int i = 0; i < 8; ++i) if (i < st) v[i] += v[i + st];
    l_run += half_combine_sum(v[0]);

    // P -> B-frags (cvt_pk + half swaps), both chunks
    u32 pk0[8], pk1[8];
    #pragma unroll
    for (int i = 0; i < 8; ++i) {
      pk0[i] = __builtin_bit_cast(u32, __builtin_amdgcn_cvt_pkrtz(p0[2 * i], p0[2 * i + 1]));
      pk1[i] = __builtin_bit_cast(u32, __builtin_amdgcn_cvt_pkrtz(p1[2 * i], p1[2 * i + 1]));
    }
    plane_swap(pk0[0], pk0[2]); plane_swap(pk0[1], pk0[3]);
    plane_swap(pk0[4], pk0[6]); plane_swap(pk0[5], pk0[7]);
    plane_swap(pk1[0], pk1[2]); plane_swap(pk1[1], pk1[3]);
    plane_swap(pk1[4], pk1[6]); plane_swap(pk1[5], pk1[7]);
    u32x4 c00 = {pk0[0], pk0[1], pk0[2], pk0[3]}, c01 = {pk0[4], pk0[5], pk0[6], pk0[7]};
    u32x4 c10 = {pk1[0], pk1[1], pk1[2], pk1[3]}, c11 = {pk1[4], pk1[5], pk1[6], pk1[7]};
    h16x8 pf[4] = {__builtin_bit_cast(h16x8, c00), __builtin_bit_cast(h16x8, c01),
                   __builtin_bit_cast(h16x8, c10), __builtin_bit_cast(h16x8, c11)};

    // PV both chunks: 12 MFMAs, 3 independent acc chains
    const u16* vb0 = &Vs[bf][0];
    const u16* vb1 = &Vs[bf][3072];
    __builtin_amdgcn_s_setprio(1);
    #pragma unroll
    for (int s2 = 0; s2 < 2; ++s2) {
      #pragma unroll
      for (int ob = 0; ob < 3; ++ob) {
        h16x8 vf0 = *(const h16x8*)(vb0 + (((s2 * 3 + ob) * 2 + h) * 32 + l31) * 8);
        acc[ob] = __builtin_amdgcn_mfma_f32_32x32x16_f16(vf0, pf[s2], acc[ob], 0, 0, 0);
        h16x8 vf1 = *(const h16x8*)(vb1 + (((s2 * 3 + ob) * 2 + h) * 32 + l31) * 8);
        acc[ob] = __builtin_amdgcn_mfma_f32_32x32x16_f16(vf1, pf[2 + s2], acc[ob], 0, 0, 0);
      }
    }
    __builtin_amdgcn_s_setprio(0);
    __builtin_amdgcn_s_barrier();
    __builtin_amdgcn_sched_barrier(0);
  }

  // epilogue: normalized partial + (m,l) per row (log2-domain m)
  float inv = 1.0f / l_run;
  int nglob = nc * 32 + l31;
  u16* yp = yP + (((size_t)sp * NB + b) * NN + nglob) * OO;
  #pragma unroll
  for (int ob = 0; ob < 3; ++ob) {
    #pragma unroll
    for (int rq = 0; rq < 4; ++rq) {
      int o0 = ob * 32 + rq * 8 + h * 4;
      u32 w0 = __builtin_bit_cast(u32,
          __builtin_amdgcn_cvt_pkrtz(acc[ob][rq * 4 + 0] * inv, acc[ob][rq * 4 + 1] * inv));
      u32 w1 = __builtin_bit_cast(u32,
          __builtin_amdgcn_cvt_pkrtz(acc[ob][rq * 4 + 2] * inv, acc[ob][rq * 4 + 3] * inv));
      uint2 pr; pr.x = w0; pr.y = w1;
      *(uint2*)&yp[o0] = pr;
    }
  }
  if (h == 0) {
    float2 v2; v2.x = m_run; v2.y = l_run;
    *(float2*)&ml[(((size_t)sp * NB + b) * NN + nglob) * 2] = v2;
  }
}

// ---------------- Kernel 3: merge partials + W projection + residual ----------------
#define YPAD 104
__global__ __launch_bounds__(256) void outproj_kernel(
    const float* __restrict__ x, const float* __restrict__ Ww,
    const float* __restrict__ Wb, const u16* __restrict__ yP,
    const float* __restrict__ ml, float* __restrict__ out)
{
  __shared__ __align__(16) u16 Wws[CC][YPAD];
  __shared__ __align__(16) u16 Ys[64][YPAD];
  const int b = blockIdx.y, n0 = blockIdx.x * 64, tid = threadIdx.x;
  const int lane = tid & 63, wv = tid >> 6, l15 = lane & 15, lg = lane >> 4;
  const size_t SB = (size_t)NB * NN;

  #pragma unroll
  for (int it = 0; it < 18; ++it) {
    int idx = tid + it * 256;
    int r = idx / 24, q = idx % 24;
    float4 v = *(const float4*)(Ww + r * OO + q * 4);
    u16x4 hh; hh[0] = f2h(v.x); hh[1] = f2h(v.y); hh[2] = f2h(v.z); hh[3] = f2h(v.w);
    *(u16x4*)&Wws[r][q * 4] = hh;
  }
  // stage Ys with in-register 3-way flash merge
  #pragma unroll
  for (int it = 0; it < 3; ++it) {
    int idx = tid + it * 256;
    int n = idx / 12, q = idx % 12;
    size_t bn = (size_t)b * NN + n0 + n;
    float m0 = ml[(0 * SB + bn) * 2], l0 = ml[(0 * SB + bn) * 2 + 1];
    float m1 = ml[(1 * SB + bn) * 2], l1 = ml[(1 * SB + bn) * 2 + 1];
    float m2 = ml[(2 * SB + bn) * 2], l2 = ml[(2 * SB + bn) * 2 + 1];
    float M = max3f(m0, m1, m2);
    float w0 = l0 * exp2f(m0 - M), w1 = l1 * exp2f(m1 - M), w2 = l2 * exp2f(m2 - M);
    float rinv = 1.0f / (w0 + w1 + w2);
    w0 *= rinv; w1 *= rinv; w2 *= rinv;
    h16x8 y0 = *(const h16x8*)(yP + (0 * SB + bn) * OO + q * 8);
    h16x8 y1 = *(const h16x8*)(yP + (1 * SB + bn) * OO + q * 8);
    h16x8 y2 = *(const h16x8*)(yP + (2 * SB + bn) * OO + q * 8);
    u32x4 packed;
    #pragma unroll
    for (int e = 0; e < 4; ++e) {
      float a = w0 * (float)y0[2 * e]     + w1 * (float)y1[2 * e]     + w2 * (float)y2[2 * e];
      float c = w0 * (float)y0[2 * e + 1] + w1 * (float)y1[2 * e + 1] + w2 * (float)y2[2 * e + 1];
      packed[e] = __builtin_bit_cast(u32, __builtin_amdgcn_cvt_pkrtz(a, c));
    }
    *(u32x4*)&Ys[n][q * 8] = packed;
  }
  __syncthreads();

  f32x4 acc[12];
  #pragma unroll
  for (int cf = 0; cf < 12; ++cf) acc[cf] = (f32x4){0.f, 0.f, 0.f, 0.f};
  #pragma unroll
  for (int ks = 0; ks < 3; ++ks) {
    h16x8 yb = *(const h16x8*)&Ys[wv * 16 + l15][ks * 32 + lg * 8];
    #pragma unroll
    for (int cf = 0; cf < 12; ++cf) {
      h16x8 wa = *(const h16x8*)&Wws[cf * 16 + l15][ks * 32 + lg * 8];
      acc[cf] = __builtin_amdgcn_mfma_f32_16x16x32_f16(wa, yb, acc[cf], 0, 0, 0);
    }
  }
  #pragma unroll
  for (int cf = 0; cf < 12; ++cf) {
    #pragma unroll
    for (int r = 0; r < 4; ++r) {
      int c = cf * 16 + lg * 4 + r;
      size_t off = ((size_t)(b * CC + c)) * NN + n0 + wv * 16 + l15;
      out[off] = acc[cf][r] + x[off] + Wb[c];
    }
  }
}

extern "C" void kernel_launch(void* const* d_in, const int* in_sizes, int n_in,
                              void* d_out, int out_size, void* d_ws, size_t ws_size,
                              hipStream_t stream) {
  const float* x    = (const float*)d_in[0];
  const float* g_w  = (const float*)d_in[1];
  const float* g_b  = (const float*)d_in[2];
  const float* th_w = (const float*)d_in[3];
  const float* th_b = (const float*)d_in[4];
  const float* ph_w = (const float*)d_in[5];
  const float* ph_b = (const float*)d_in[6];
  const float* W_w  = (const float*)d_in[7];
  const float* W_b  = (const float*)d_in[8];
  float* out = (float*)d_out;

  char* ws = (char*)d_ws;
  const size_t projB = (size_t)NB * NN * OO * sizeof(u16);   // 6.29 MB
  u16* QB   = (u16*)ws;
  u16* KA   = (u16*)(ws + projB);
  u16* VA   = (u16*)(ws + 2 * projB);
  u16* yP   = (u16*)(ws + 3 * projB);                        // 3 * projB
  float* ml = (float*)(ws + 6 * projB);                      // 786 KB

  dim3 blk(256);
  dim3 gproj(64, NB);
  hipLaunchKernelGGL(proj_kernel, gproj, blk, 0, stream,
                     x, g_w, g_b, th_w, th_b, ph_w, ph_b, QB, KA, VA);
  dim3 gattn(NB, 32, NSPLIT);
  hipLaunchKernelGGL(attn_kernel, gattn, blk, 0, stream, QB, KA, VA, yP, ml);
  dim3 gout(64, NB);
  hipLaunchKernelGGL(outproj_kernel, gout, blk, 0, stream, x, W_w, W_b, yP, ml, out);
}